// Round 8
// baseline (10680.898 us; speedup 1.0000x reference)
//
#include <hip/hip_runtime.h>
#include <math.h>

// GRU: B=64, S=512, I=256, H=1024, O=256.
// Round 8: R7 + the missing __syncthreads() between recurrence-loop exit and
// head LDS reuse. R7's NaN root cause: with no block-wide sync in the loop,
// a finished wave overwrote the weight LDS region (hsm staging) while
// sibling waves were still reading weights -> fp32 low-half bit patterns
// read as bf16 NaN -> NaN propagation. Everything else identical to R7:
//   - cooperative 64 blocks x 256 thr, smem 123,648 (R3-proven envelope)
//   - per-wave flag arrays, no atomics, no fences in the loop:
//     producer: sc0sc1 data stores -> vmcnt(0) -> flag store (relaxed,system)
//     consumer: 64-lane coalesced flag poll + __ballot; data via system-scope
//     (LLC-direct) loads -> NO cache invalidation anywhere
//   - x-part MFMAs (z,r,n) overlapped before the wait

typedef __attribute__((ext_vector_type(8))) short bf8;
typedef __attribute__((ext_vector_type(4))) short bf4;
typedef __attribute__((ext_vector_type(4))) float f32x4;
typedef unsigned long long u64;

#define KP 1288   // LDS K-stride (elems), R3-proven
#define MFMA __builtin_amdgcn_mfma_f32_16x16x32_bf16

__device__ __forceinline__ short f2b(float f) {
  unsigned u = __builtin_bit_cast(unsigned, f);
  u += 0x7fffu + ((u >> 16) & 1u);          // RNE
  return (short)(u >> 16);
}
__device__ __forceinline__ float sigm(float x) { return 1.f / (1.f + __expf(-x)); }
__device__ __forceinline__ float tanh_(float x) {
  float t = fminf(fmaxf(x, -12.f), 12.f);
  float e = __expf(2.f * t);
  return (e - 1.f) / (e + 1.f);
}

// write-through stores to LLC (coherence point) -- R3-proven
__device__ __forceinline__ void st_b16_llc(short* p, short v) {
  int vv = (int)(unsigned short)v;
  asm volatile("global_store_short %0, %1, off sc0 sc1" :: "v"(p), "v"(vv) : "memory");
}
__device__ __forceinline__ void st_f32_llc(float* p, float v) {
  asm volatile("global_store_dword %0, %1, off sc0 sc1" :: "v"(p), "v"(v) : "memory");
}
__device__ __forceinline__ void wait_vm0() {
  asm volatile("s_waitcnt vmcnt(0)" ::: "memory");
}

// 16B A-fragment straight from LLC via 2x u64 system-scope loads
__device__ __forceinline__ bf8 ld_frag_sys(const short* p) {
  u64 lo = __hip_atomic_load((const u64*)p,     __ATOMIC_RELAXED, __HIP_MEMORY_SCOPE_SYSTEM);
  u64 hi = __hip_atomic_load((const u64*)p + 1, __ATOMIC_RELAXED, __HIP_MEMORY_SCOPE_SYSTEM);
  union { u64 q[2]; bf8 v; } u;
  u.q[0] = lo; u.q[1] = hi;
  return u.v;
}

// wave-wide poll: all 64 lanes load one flag each; done when all >= target
__device__ __forceinline__ void wait_row(const int* row, int lane, int target) {
  for (;;) {
    int v = __hip_atomic_load(row + lane, __ATOMIC_RELAXED, __HIP_MEMORY_SCOPE_SYSTEM);
    if (__ballot(v < target) == 0ull) break;
  }
  __atomic_signal_fence(__ATOMIC_ACQUIRE);   // compiler barrier only
}

// ---------------- preprocessing (unchanged, proven) ----------------

__global__ __launch_bounds__(256) void cvt_x(const float* __restrict__ in,
                                             short* __restrict__ outp) {
  int idx = blockIdx.x * 256 + threadIdx.x;   // 8192 blocks x 4 floats
  float4 v = ((const float4*)in)[idx];
  bf4 o;
  o[0] = f2b(v.x); o[1] = f2b(v.y); o[2] = f2b(v.z); o[3] = f2b(v.w);
  ((bf4*)outp)[idx] = o;
}

// Wt[g][j][k] = bf16( k<1024 ? Wh_g[k][j] : Wx_g[k-1024][j] ), k-contiguous.
__global__ __launch_bounds__(256) void pack_w(
    const float* __restrict__ Whz, const float* __restrict__ Wxz,
    const float* __restrict__ Whr, const float* __restrict__ Wxr,
    const float* __restrict__ Whh, const float* __restrict__ Wxh,
    short* __restrict__ Wt) {
  int b = blockIdx.x;
  int g = b / 320, rem = b % 320;
  int jt = rem / 20, kt = rem % 20;
  int j0 = jt * 64, k0 = kt * 64;
  const float* Wh = (g == 0) ? Whz : (g == 1) ? Whr : Whh;
  const float* Wx = (g == 0) ? Wxz : (g == 1) ? Wxr : Wxh;
  __shared__ short tile[64 * 72];
  int tid = threadIdx.x;
  for (int p = 0; p < 16; ++p) {
    int r = p * 4 + (tid >> 6);
    int cc = tid & 63;
    int k = k0 + r;
    float v = (k < 1024) ? Wh[(size_t)k * 1024 + j0 + cc]
                         : Wx[(size_t)(k - 1024) * 1024 + j0 + cc];
    tile[r * 72 + cc] = f2b(v);
  }
  __syncthreads();
  int j = tid >> 2, kq = tid & 3;
  bf8 v0, v1;
#pragma unroll
  for (int i = 0; i < 8; ++i) {
    v0[i] = tile[(kq * 16 + i) * 72 + j];
    v1[i] = tile[(kq * 16 + 8 + i) * 72 + j];
  }
  short* dst = Wt + ((size_t)(g * 1024 + j0 + j)) * 1280 + k0 + kq * 16;
  *(bf8*)dst = v0;
  *((bf8*)dst + 1) = v1;
}

// ---------------- persistent GRU kernel ----------------
// ctrl (ints): flagA[w][c] at w*64+c (w<4,c<64); flagH[w][c] at 256+w*64+c.
__global__ __launch_bounds__(256, 1) void gru_flags(
    const short* __restrict__ xx,   // x bf16 [64][512][256]
    const short* __restrict__ Wt,   // packed weights bf16 [3][1024][1280]
    float* __restrict__ h32,        // fp32 h final (written s=511)
    short* __restrict__ h16,        // bf16 h (exchange)
    short* __restrict__ ab,         // bf16 r*h (exchange)
    int* __restrict__ ctrl,
    const float* __restrict__ bz, const float* __restrict__ br,
    const float* __restrict__ bh,
    const float* __restrict__ Wf, const float* __restrict__ bfv,
    float* __restrict__ out) {
  extern __shared__ short lds[];                 // 48*KP weight elems

  const int tid = threadIdx.x;
  const int w = tid >> 6, lane = tid & 63;
  const int row16 = lane & 15, quad = lane >> 4, ko = quad * 8;
  const int j0 = blockIdx.x * 16;
  const int bg0 = w * 16;
  const int bA = bg0 + row16;                    // batch row for A-loads

  const float bzv = bz[j0 + row16];
  const float brv = br[j0 + row16];
  const float bhv = bh[j0 + row16];

  // weights -> LDS (48 cols x 1280, transposed, bf16) -- R3-proven layout
  for (int ch = tid; ch < 48 * 160; ch += 256) {
    int lc = ch / 160, c8 = ch % 160;
    int g = lc >> 4, j = j0 + (lc & 15);
    *(bf8*)(lds + lc * KP + c8 * 8) =
        *(const bf8*)(Wt + ((size_t)(g * 1024 + j)) * 1280 + c8 * 8);
  }
  __syncthreads();

  const short* wzp = lds + row16 * KP;
  const short* wrp = lds + (16 + row16) * KP;
  const short* wnp = lds + (32 + row16) * KP;

  int* fA = ctrl + w * 64;                       // my wave's flag rows
  int* fH = ctrl + 256 + w * 64;

  float hreg[4] = {0.f, 0.f, 0.f, 0.f};
  float zreg[4];

  for (int s = 0; s < 512; ++s) {
    const short* xrow = xx + ((size_t)bA * 512 + s) * 256;

    // ---- overlap zone: x-part MFMAs for z, r, n (no recurrent dep) ----
    bf8 xa[8];
#pragma unroll
    for (int kt = 0; kt < 8; ++kt) xa[kt] = *(const bf8*)(xrow + kt * 32 + ko);
    f32x4 az0 = {0,0,0,0}, az1 = {0,0,0,0};
    f32x4 ar0 = {0,0,0,0}, ar1 = {0,0,0,0};
    f32x4 an0 = {0,0,0,0}, an1 = {0,0,0,0};
#pragma unroll
    for (int kt = 0; kt < 8; ++kt) {
      int k = 1024 + kt * 32 + ko;
      f32x4& az = (kt & 1) ? az1 : az0;
      f32x4& ar = (kt & 1) ? ar1 : ar0;
      f32x4& an = (kt & 1) ? an1 : an0;
      az = MFMA(xa[kt], *(const bf8*)(wzp + k), az, 0, 0, 0);
      ar = MFMA(xa[kt], *(const bf8*)(wrp + k), ar, 0, 0, 0);
      an = MFMA(xa[kt], *(const bf8*)(wnp + k), an, 0, 0, 0);
    }

    // ---- wait for h_{s-1} (wave-row-matched flags), then h-part ----
    if (s > 0) wait_row(fH, lane, s);
    const short* hbase = h16 + bA * 1024;
    bf8 ha[32];
#pragma unroll
    for (int kt = 0; kt < 32; ++kt) ha[kt] = ld_frag_sys(hbase + kt * 32 + ko);
#pragma unroll
    for (int kt = 0; kt < 32; ++kt) {
      int k = kt * 32 + ko;
      f32x4& az = (kt & 1) ? az1 : az0;
      f32x4& ar = (kt & 1) ? ar1 : ar0;
      az = MFMA(ha[kt], *(const bf8*)(wzp + k), az, 0, 0, 0);
      ar = MFMA(ha[kt], *(const bf8*)(wrp + k), ar, 0, 0, 0);
    }
    f32x4 azs = az0 + az1, ars = ar0 + ar1;
#pragma unroll
    for (int i = 0; i < 4; ++i) {
      zreg[i] = sigm(azs[i] + bzv);
      float r = sigm(ars[i] + brv);
      st_b16_llc(&ab[(bg0 + quad * 4 + i) * 1024 + j0 + row16], f2b(r * hreg[i]));
    }
    wait_vm0();                                  // data visible at LLC
    if (lane == 0)
      __hip_atomic_store(fA + blockIdx.x, s + 1, __ATOMIC_RELAXED,
                         __HIP_MEMORY_SCOPE_SYSTEM);

    // ---- phase 2: n, h update ----
    wait_row(fA, lane, s + 1);
    const short* abase = ab + bA * 1024;
    bf8 aa[32];
#pragma unroll
    for (int kt = 0; kt < 32; ++kt) aa[kt] = ld_frag_sys(abase + kt * 32 + ko);
#pragma unroll
    for (int kt = 0; kt < 32; ++kt) {
      int k = kt * 32 + ko;
      f32x4& an = (kt & 1) ? an1 : an0;
      an = MFMA(aa[kt], *(const bf8*)(wnp + k), an, 0, 0, 0);
    }
    f32x4 ans = an0 + an1;
#pragma unroll
    for (int i = 0; i < 4; ++i) {
      float n = tanh_(ans[i] + bhv);
      float hn = fmaf(zreg[i], n - hreg[i], hreg[i]);   // (1-z)h + z*n
      hreg[i] = hn;
      int idx = (bg0 + quad * 4 + i) * 1024 + j0 + row16;
      st_b16_llc(&h16[idx], f2b(hn));
      if (s == 511) st_f32_llc(&h32[idx], hn);
    }
    wait_vm0();
    if (lane == 0)
      __hip_atomic_store(fH + blockIdx.x, s + 1, __ATOMIC_RELAXED,
                         __HIP_MEMORY_SCOPE_SYSTEM);
  }

  // ALL waves of this block must exit the loop before LDS is reused:
  // without this, a finished wave stomps weight LDS that siblings still read
  // (R7's NaN root cause).
  __syncthreads();

  // ---- head: block b = batch row b; out[b][tid] = h32[b].Wf[:,tid]+bf ----
  {
    int b = blockIdx.x;
    const int* fhrow = ctrl + 256 + (b >> 4) * 64;  // wave that owns row b
    wait_row(fhrow, lane, 512);
    __syncthreads();                                // all waves' waits done
    float* hsm = (float*)lds;                       // safe to reuse now
    const float* hg = h32 + (size_t)b * 1024;
    u64 lo = __hip_atomic_load((const u64*)(hg + tid * 4),     __ATOMIC_RELAXED, __HIP_MEMORY_SCOPE_SYSTEM);
    u64 hi = __hip_atomic_load((const u64*)(hg + tid * 4) + 1, __ATOMIC_RELAXED, __HIP_MEMORY_SCOPE_SYSTEM);
    ((u64*)hsm)[tid * 2]     = lo;
    ((u64*)hsm)[tid * 2 + 1] = hi;
    __syncthreads();
    float acc = bfv[tid];
#pragma unroll 8
    for (int k = 0; k < 1024; ++k)
      acc = fmaf(hsm[k], Wf[(size_t)k * 256 + tid], acc);
    out[b * 256 + tid] = acc;
  }
}

// ---------------- host ----------------
extern "C" void kernel_launch(void* const* d_in, const int* in_sizes, int n_in,
                              void* d_out, int out_size, void* d_ws, size_t ws_size,
                              hipStream_t stream) {
  const float* x   = (const float*)d_in[0];
  const float* Wxz = (const float*)d_in[1];
  const float* Whz = (const float*)d_in[2];
  const float* Wxr = (const float*)d_in[3];
  const float* Whr = (const float*)d_in[4];
  const float* Wxh = (const float*)d_in[5];
  const float* Whh = (const float*)d_in[6];
  const float* bz  = (const float*)d_in[7];
  const float* br  = (const float*)d_in[8];
  const float* bh  = (const float*)d_in[9];
  const float* Wf  = (const float*)d_in[10];
  const float* bfp = (const float*)d_in[11];
  float* out = (float*)d_out;

  char* ws = (char*)d_ws;                   // R3-proven layout
  float* h32 = (float*)(ws + 0);            // 256 KB
  short* h16 = (short*)(ws + 262144);       // 128 KB
  int*   ctrl= (int*)  (ws + 393216);       // 4 KB (512 flags used)
  short* ab  = (short*)(ws + 397312);       // 128 KB
  short* xx  = (short*)(ws + 528384);       // 16 MB
  short* Wt  = (short*)(ws + 17305600);     // 7.86 MB (total ~24.3 MB)

  hipMemsetAsync(d_ws, 0, 397312, stream);  // h32 + h16 + ctrl = zeros

  cvt_x<<<8192, 256, 0, stream>>>(x, xx);
  pack_w<<<960, 256, 0, stream>>>(Whz, Wxz, Whr, Wxr, Whh, Wxh, Wt);

  const int smem = 48 * KP * 2;             // 123,648 B -- R3-proven
  hipFuncSetAttribute((const void*)gru_flags,
                      hipFuncAttributeMaxDynamicSharedMemorySize, smem);
  void* args[] = {&xx, &Wt, &h32, &h16, &ab, &ctrl,
                  (void*)&bz, (void*)&br, (void*)&bh,
                  (void*)&Wf, (void*)&bfp, &out};
  hipLaunchCooperativeKernel((const void*)gru_flags, dim3(64), dim3(256),
                             args, smem, stream);
}